// Round 2
// baseline (332.382 us; speedup 1.0000x reference)
//
#include <hip/hip_runtime.h>

#define BN1 160
#define BN2 1024
#define BD  256

// Folded transcendental constants:
//   gb * log1p(e^{-x/gb}) == (gb*ln2) * log2(1 + 2^{-x * log2e/gb})
#define GB_LN2 0.0024953256f   // 0.0036 * ln(2)
#define K2     400.74862f      // log2(e) / 0.0036

typedef float f32x4 __attribute__((ext_vector_type(4)));

// Hardware transcendental ops (collision-proof names; map to v_exp_f32 / v_log_f32).
#define EXP2F(x) __builtin_amdgcn_exp2f(x)   // 2^x
#define LOG2F(x) __builtin_amdgcn_logf(x)    // log2(x)

// Precomputed sigmoid offsets (rewritten every launch; no d_ws dependency).
__device__ float g_z1min[BN1 * BD];
__device__ float g_z1max[BN1 * BD];
__device__ float g_z2min[BN2 * BD];
__device__ float g_z2max[BN2 * BD];

__device__ __forceinline__ float softplus10(float x) {
    // softplus(10x)/10, stable: (max(y,0) + log1p(exp(-|y|))) / 10
    float y = 10.0f * x;
    float t = __expf(-fabsf(y));
    return (fmaxf(y, 0.0f) + __logf(1.0f + t)) * 0.1f;
}

__device__ __forceinline__ float sigmoidf(float x) {
    return 1.0f / (1.0f + __expf(-x));
}

__global__ __launch_bounds__(256) void precompute_kernel(
        const float* __restrict__ box1s, const float* __restrict__ box2s) {
    int idx = blockIdx.x * 256 + threadIdx.x;
    if (idx < BN2 * BD) {
        int n = idx >> 8;          // / BD
        int d = idx & (BD - 1);    // % BD
        float c  = box2s[n * 2 * BD + d];
        float sp = softplus10(box2s[n * 2 * BD + BD + d]);
        g_z2min[idx] = sigmoidf(c - sp);
        g_z2max[idx] = sigmoidf(c + sp);
    } else {
        int j = idx - BN2 * BD;
        if (j < BN1 * BD) {
            int n = j >> 8;
            int d = j & (BD - 1);
            float c  = box1s[n * 2 * BD + d];
            float sp = softplus10(box1s[n * 2 * BD + BD + d]);
            g_z1min[j] = sigmoidf(c - sp);
            g_z1max[j] = sigmoidf(c + sp);
        }
    }
}

union F4 {
    f32x4 v;
    float f[4];
};

__device__ __forceinline__ float gumbel_min(float x, float y) {
    float m = fmaxf(x, y);
    float c = GB_LN2 * LOG2F(1.0f + EXP2F(-fabsf(x - y) * K2));
    return fmaxf(m + c, m);   // inter_min (outer max kept for exact ref match)
}

__device__ __forceinline__ float gumbel_max(float x, float y) {
    float m = fminf(x, y);
    float c = GB_LN2 * LOG2F(1.0f + EXP2F(-fabsf(x - y) * K2));
    return fminf(m - c, m);   // inter_max
}

// Each block owns 8 consecutive i1 rows of ONE i2 (160 % 8 == 0, so blocks
// never straddle an i2 boundary). 4 waves/block, each wave owns 2 rows.
// Per thread: a/A loaded once, reused for both rows; 4 independent
// nontemporal float4 stores (output is never re-read -> don't allocate in L2,
// keeping the 2.4 MB sigmoid tables L2-resident).
__global__ __launch_bounds__(256) void pairs_kernel(float* __restrict__ out) {
    const int t   = threadIdx.x;
    const int bid = blockIdx.x;
    const int i2  = bid / 20;                            // 20 blocks per i2
    const int i1  = (bid - i2 * 20) * 8 + ((t >> 6) << 1); // wave's first row
    const int d0  = (t & 63) << 2;

    F4 a, A, b0, B0, b1, B1;
    a.v  = *(const f32x4*)(g_z2min + i2 * BD + d0);
    A.v  = *(const f32x4*)(g_z2max + i2 * BD + d0);
    b0.v = *(const f32x4*)(g_z1min + i1 * BD + d0);
    B0.v = *(const f32x4*)(g_z1max + i1 * BD + d0);
    b1.v = *(const f32x4*)(g_z1min + (i1 + 1) * BD + d0);
    B1.v = *(const f32x4*)(g_z1max + (i1 + 1) * BD + d0);

    F4 o00, o01, o10, o11;   // oRJ: row R, J=0 -> inter_min, J=1 -> inter_max
#pragma unroll
    for (int j = 0; j < 4; ++j) {
        const float av = a.f[j], Av = A.f[j];
        o00.f[j] = gumbel_min(av, b0.f[j]);
        o01.f[j] = gumbel_max(Av, B0.f[j]);
        o10.f[j] = gumbel_min(av, b1.f[j]);
        o11.f[j] = gumbel_max(Av, B1.f[j]);
    }

    const size_t half = (size_t)BN2 * BN1 * BD;
    const size_t base = (size_t)(i2 * BN1 + i1) * BD + d0;
    __builtin_nontemporal_store(o00.v, (f32x4*)(out + base));
    __builtin_nontemporal_store(o10.v, (f32x4*)(out + base + BD));
    __builtin_nontemporal_store(o01.v, (f32x4*)(out + half + base));
    __builtin_nontemporal_store(o11.v, (f32x4*)(out + half + base + BD));
}

extern "C" void kernel_launch(void* const* d_in, const int* in_sizes, int n_in,
                              void* d_out, int out_size, void* d_ws, size_t ws_size,
                              hipStream_t stream) {
    const float* box1s = (const float*)d_in[0];
    const float* box2s = (const float*)d_in[1];
    float* out = (float*)d_out;

    // (BN2*BD + BN1*BD) = 303104 elements = exactly 1184 blocks of 256
    precompute_kernel<<<1184, 256, 0, stream>>>(box1s, box2s);

    // BN2 * (BN1/8) blocks, 8 rows per block
    pairs_kernel<<<BN2 * (BN1 / 8), 256, 0, stream>>>(out);
}

// Round 3
// 328.327 us; speedup vs baseline: 1.0123x; 1.0123x over previous
//
#include <hip/hip_runtime.h>

#define BN1 160
#define BN2 1024
#define BD  256

// Folded transcendental constants:
//   gb * log1p(e^{-x/gb}) == (gb*ln2) * log2(1 + 2^{-x * log2e/gb})
#define GB_LN2 0.0024953256f   // 0.0036 * ln(2)
#define K2     400.74862f      // log2(e) / 0.0036

typedef float f32x4 __attribute__((ext_vector_type(4)));

// Hardware transcendental ops (collision-proof names; map to v_exp_f32 / v_log_f32).
#define EXP2F(x) __builtin_amdgcn_exp2f(x)   // 2^x
#define LOG2F(x) __builtin_amdgcn_logf(x)    // log2(x)

// Precomputed sigmoid offsets (rewritten every launch; no d_ws dependency).
__device__ float g_z1min[BN1 * BD];
__device__ float g_z1max[BN1 * BD];
__device__ float g_z2min[BN2 * BD];
__device__ float g_z2max[BN2 * BD];

__device__ __forceinline__ float softplus10(float x) {
    float y = 10.0f * x;
    float t = __expf(-fabsf(y));
    return (fmaxf(y, 0.0f) + __logf(1.0f + t)) * 0.1f;
}

__device__ __forceinline__ float sigmoidf(float x) {
    return 1.0f / (1.0f + __expf(-x));
}

__global__ __launch_bounds__(256) void precompute_kernel(
        const float* __restrict__ box1s, const float* __restrict__ box2s) {
    int idx = blockIdx.x * 256 + threadIdx.x;
    if (idx < BN2 * BD) {
        int n = idx >> 8;
        int d = idx & (BD - 1);
        float c  = box2s[n * 2 * BD + d];
        float sp = softplus10(box2s[n * 2 * BD + BD + d]);
        g_z2min[idx] = sigmoidf(c - sp);
        g_z2max[idx] = sigmoidf(c + sp);
    } else {
        int j = idx - BN2 * BD;
        if (j < BN1 * BD) {
            int n = j >> 8;
            int d = j & (BD - 1);
            float c  = box1s[n * 2 * BD + d];
            float sp = softplus10(box1s[n * 2 * BD + BD + d]);
            g_z1min[j] = sigmoidf(c - sp);
            g_z1max[j] = sigmoidf(c + sp);
        }
    }
}

union F4 {
    f32x4 v;
    float f[4];
};

__device__ __forceinline__ float gumbel_min(float x, float y) {
    float m = fmaxf(x, y);
    float c = GB_LN2 * LOG2F(1.0f + EXP2F(-fabsf(x - y) * K2));
    return fmaxf(m + c, m);   // inter_min
}

__device__ __forceinline__ float gumbel_max(float x, float y) {
    float m = fminf(x, y);
    float c = GB_LN2 * LOG2F(1.0f + EXP2F(-fabsf(x - y) * K2));
    return fminf(m - c, m);   // inter_max
}

// pairs: 5120 blocks x 256 threads. Wave w of block b owns 8 CONTIGUOUS rows
// starting at r0 = (b*4+w)*8. Since 160 % 8 == 0, an 8-row run never straddles
// an i2 boundary -> a/A loaded once per wave. b/B for row i+1 are prefetched
// while row i computes/stores (software pipeline). 16 x 1KiB wave-stores per
// wave, fully unrolled. Chunked XCD swizzle: each XCD writes one contiguous
// ~42 MB output region and reads a contiguous i2-table slice from its own L2.
__global__ __launch_bounds__(256) void pairs_kernel(float* __restrict__ out) {
    const int t    = threadIdx.x;
    const int wave = t >> 6;
    const int lane = t & 63;
    const int bid  = (blockIdx.x & 7) * 640 + (blockIdx.x >> 3);  // 5120 = 8*640
    const int r0   = (bid * 4 + wave) * 8;       // first row (row = i2*BN1 + i1)
    const int i2   = r0 / BN1;
    const int i1_0 = r0 - i2 * BN1;
    const int d0   = lane << 2;

    F4 a, A;
    a.v = *(const f32x4*)(g_z2min + i2 * BD + d0);
    A.v = *(const f32x4*)(g_z2max + i2 * BD + d0);

    const size_t half = (size_t)BN2 * BN1 * BD;
    size_t base = (size_t)r0 * BD + d0;

    F4 b, B, bn, Bn;
    bn.v = *(const f32x4*)(g_z1min + i1_0 * BD + d0);
    Bn.v = *(const f32x4*)(g_z1max + i1_0 * BD + d0);

#pragma unroll
    for (int i = 0; i < 8; ++i) {
        b = bn; B = Bn;
        if (i < 7) {
            bn.v = *(const f32x4*)(g_z1min + (i1_0 + i + 1) * BD + d0);
            Bn.v = *(const f32x4*)(g_z1max + (i1_0 + i + 1) * BD + d0);
        }
        F4 o0, o1;
#pragma unroll
        for (int j = 0; j < 4; ++j) {
            o0.f[j] = gumbel_min(a.f[j], b.f[j]);
            o1.f[j] = gumbel_max(A.f[j], B.f[j]);
        }
        *(f32x4*)(out + base)        = o0.v;
        *(f32x4*)(out + half + base) = o1.v;
        base += BD;
    }
}

extern "C" void kernel_launch(void* const* d_in, const int* in_sizes, int n_in,
                              void* d_out, int out_size, void* d_ws, size_t ws_size,
                              hipStream_t stream) {
    const float* box1s = (const float*)d_in[0];
    const float* box2s = (const float*)d_in[1];
    float* out = (float*)d_out;

    precompute_kernel<<<1184, 256, 0, stream>>>(box1s, box2s);

    // 163840 rows / (4 waves * 8 rows per wave) = 5120 blocks
    pairs_kernel<<<5120, 256, 0, stream>>>(out);
}